// Round 1
// baseline (408.058 us; speedup 1.0000x reference)
//
#include <hip/hip_runtime.h>
#include <hip/hip_bf16.h>

// Problem constants (fixed by setup_inputs): B=2, T=4 -> BT=8 clouds per side,
// N=16384 points per cloud, 3 coords. Pads (1000,1000,1000) contribute exactly
// 0 to sum and 0 to the >0 count, so only real points are processed.
#define NPTS   16384
#define NJOBS  16          // 8 (bt) x 2 (direction)
#define BLK    256         // threads per block (4 waves)
#define NQ     8           // queries per thread
#define QB     (BLK * NQ)  // 2048 queries per block
#define QBLOCKS (NPTS / QB)       // 8
#define KSPLIT  4
#define KEYS_PER_SPLIT (NPTS / KSPLIT)  // 4096
#define TILE    2048       // keys per LDS tile (32 KiB as float4)

// monotonic float<->int mapping so signed-int atomicMin == float min
__device__ __forceinline__ int f2key(float f) {
    int b = __float_as_int(f);
    return (b >= 0) ? b : (b ^ 0x7fffffff);
}
__device__ __forceinline__ float key2f(int k) {
    int b = (k >= 0) ? k : (k ^ 0x7fffffff);
    return __int_as_float(b);
}

__global__ __launch_bounds__(BLK, 2)
void cham_pass1(const float* __restrict__ op, const float* __restrict__ tp,
                int* __restrict__ wmin) {
    __shared__ float4 kls[TILE];

    const int bid = blockIdx.x;
    const int job = bid >> 5;          // 32 blocks per job (8 qb x 4 ks)
    const int rem = bid & 31;
    const int qb  = rem >> 2;
    const int ks  = rem & 3;
    const int bt  = job >> 1;
    const int dir = job & 1;

    const float* base_o = op + (size_t)bt * NPTS * 3;
    const float* base_t = tp + (size_t)bt * NPTS * 3;
    const float* qp = (dir == 0) ? base_o : base_t;   // queries
    const float* kp = (dir == 0) ? base_t : base_o;   // keys

    const int tid = threadIdx.x;

    // load this thread's 8 queries, precompute -2*q
    float qsx[NQ], qsy[NQ], qsz[NQ], m[NQ];
    const float* q0 = qp + (size_t)qb * QB * 3;
    #pragma unroll
    for (int q = 0; q < NQ; ++q) {
        const int qi = q * BLK + tid;
        const float x = q0[qi * 3 + 0];
        const float y = q0[qi * 3 + 1];
        const float z = q0[qi * 3 + 2];
        qsx[q] = -2.0f * x;
        qsy[q] = -2.0f * y;
        qsz[q] = -2.0f * z;
        m[q]   = 3.0e38f;
    }

    const float* k0 = kp + (size_t)ks * KEYS_PER_SPLIT * 3;

    for (int t = 0; t < KEYS_PER_SPLIT; t += TILE) {
        // stage TILE keys into LDS as (x, y, z, x^2+y^2+z^2)
        #pragma unroll
        for (int i = tid; i < TILE; i += BLK) {
            const float x = k0[(t + i) * 3 + 0];
            const float y = k0[(t + i) * 3 + 1];
            const float z = k0[(t + i) * 3 + 2];
            kls[i] = make_float4(x, y, z, fmaf(x, x, fmaf(y, y, z * z)));
        }
        __syncthreads();

        // min over tile: per pair, 3 FMA + min (min3-fusable)
        #pragma unroll 4
        for (int j = 0; j < TILE; j += 2) {
            const float4 ka = kls[j];
            const float4 kb = kls[j + 1];
            #pragma unroll
            for (int q = 0; q < NQ; ++q) {
                const float da = fmaf(qsx[q], ka.x, fmaf(qsy[q], ka.y, fmaf(qsz[q], ka.z, ka.w)));
                const float db = fmaf(qsx[q], kb.x, fmaf(qsy[q], kb.y, fmaf(qsz[q], kb.z, kb.w)));
                m[q] = fminf(m[q], fminf(da, db));
            }
        }
        __syncthreads();
    }

    // combine across the 4 key-splits via int-mapped atomicMin
    int* wj = wmin + job * NPTS + qb * QB;
    #pragma unroll
    for (int q = 0; q < NQ; ++q) {
        atomicMin(&wj[q * BLK + tid], f2key(m[q]));
    }
}

__global__ void cham_pass2(const float* __restrict__ op, const float* __restrict__ tp,
                           const int* __restrict__ wmin, float* __restrict__ ws2) {
    const int job = blockIdx.x;
    const int bt  = job >> 1;
    const int dir = job & 1;
    const float* base_o = op + (size_t)bt * NPTS * 3;
    const float* base_t = tp + (size_t)bt * NPTS * 3;
    const float* qp = (dir == 0) ? base_o : base_t;
    const int tid = threadIdx.x;

    float S = 0.0f, P = 0.0f;
    for (int i = tid; i < NPTS; i += BLK) {
        const float x = qp[i * 3 + 0];
        const float y = qp[i * 3 + 1];
        const float z = qp[i * 3 + 2];
        const float q2 = fmaf(x, x, fmaf(y, y, z * z));
        const float mm = key2f(wmin[job * NPTS + i]);
        const float d = fmaxf(q2 + mm, 0.0f);
        S += d;
        P += (d > 0.0f) ? 1.0f : 0.0f;
    }

    // wave reduce (width 64), then cross-wave via LDS
    #pragma unroll
    for (int o = 32; o > 0; o >>= 1) {
        S += __shfl_down(S, o, 64);
        P += __shfl_down(P, o, 64);
    }
    __shared__ float sS[4], sP[4];
    const int wv = tid >> 6;
    if ((tid & 63) == 0) { sS[wv] = S; sP[wv] = P; }
    __syncthreads();
    if (tid == 0) {
        const float s = sS[0] + sS[1] + sS[2] + sS[3];
        const float p = sP[0] + sP[1] + sP[2] + sP[3];
        ws2[job * 2 + 0] = s;
        ws2[job * 2 + 1] = p;
    }
}

__global__ void cham_pass3(const float* __restrict__ ws2, float* __restrict__ out) {
    __shared__ float dc[8];
    const int t = threadIdx.x;
    if (t < 8) {
        const float s0 = ws2[(t * 2 + 0) * 2 + 0];
        const float p0 = ws2[(t * 2 + 0) * 2 + 1];
        const float s1 = ws2[(t * 2 + 1) * 2 + 0];
        const float p1 = ws2[(t * 2 + 1) * 2 + 1];
        dc[t] = s0 / p0 + s1 / p1;
    }
    __syncthreads();
    // out[0..3]  = per-future-step mean over batch (B=2)
    // out[4..11] = chamfer_distances_tensor reshaped (T=4, B=2) row-major
    if (t < 8) out[4 + t] = dc[t];
    if (t < 4) out[t] = 0.5f * (dc[2 * t] + dc[2 * t + 1]);
}

extern "C" void kernel_launch(void* const* d_in, const int* in_sizes, int n_in,
                              void* d_out, int out_size, void* d_ws, size_t ws_size,
                              hipStream_t stream) {
    const float* op = (const float*)d_in[0];
    const float* tp = (const float*)d_in[1];
    int*   wmin = (int*)d_ws;                                   // NJOBS*NPTS ints = 1 MiB
    float* ws2  = (float*)((char*)d_ws + (size_t)NJOBS * NPTS * sizeof(int));
    float* out  = (float*)d_out;

    // 0x7F7F7F7F is a huge positive int-mapped float -> valid atomicMin identity
    hipMemsetAsync(d_ws, 0x7F, (size_t)NJOBS * NPTS * sizeof(int), stream);

    cham_pass1<<<NJOBS * QBLOCKS * KSPLIT, BLK, 0, stream>>>(op, tp, wmin);
    cham_pass2<<<NJOBS, BLK, 0, stream>>>(op, tp, wmin, ws2);
    cham_pass3<<<1, 64, 0, stream>>>(ws2, out);
}